// Round 12
// baseline (143.087 us; speedup 1.0000x reference)
//
#include <hip/hip_runtime.h>
#include <math.h>

#define DK 32
#define OUT_DIM 32

typedef float    f32x4 __attribute__((ext_vector_type(4)));
typedef _Float16 h2    __attribute__((ext_vector_type(2)));
typedef _Float16 h8    __attribute__((ext_vector_type(8)));

#if __has_builtin(__builtin_amdgcn_fdot2)
#define FDOT2(a, b, c) __builtin_amdgcn_fdot2((a), (b), (c), false)
#else
#define FDOT2(a, b, c) ((c) + (float)(a).x * (float)(b).x + (float)(a).y * (float)(b).y)
#endif

__device__ __forceinline__ h2 as_h2(unsigned u) {
    union { unsigned u; h2 h; } v; v.u = u; return v.h;
}
__device__ __forceinline__ unsigned as_u32(h2 h) {
    union { unsigned u; h2 h; } v; v.h = h; return v.u;
}
__device__ __forceinline__ h2 shfl_xor_h2(h2 v, int m) {
    union { unsigned u; h2 h; } x; x.h = v;
    x.u = (unsigned)__shfl_xor((int)x.u, m);
    return x.h;
}

// Fused prep: (a) row_ptr[n] = first edge with dst >= n (boundary detect on
// sorted dst); (b) KVH: per node row of 32 dwords, chunk c (dims 4c..4c+3)
// = {f16(K[4c..4c+1]), f16(K[4c+2..3]), f16(V[4c..4c+1]), f16(V[4c+2..3])}
// so one 128 B row carries both K and V as f16 pairs ready for
// v_dot2_f32_f16 / v_pk_fma_f16.
__global__ void prep_kernel(const int* __restrict__ dst,
                            const float* __restrict__ K,
                            const float* __restrict__ V,
                            int E, int N,
                            int* __restrict__ row_ptr,
                            unsigned* __restrict__ KVH) {
    const int t = blockIdx.x * blockDim.x + threadIdx.x;
    if (t < E) {
        const int cur  = dst[t];
        const int prev = (t == 0) ? -1 : dst[t - 1];
        for (int j = prev + 1; j <= cur; ++j) row_ptr[j] = t;
        if (t == E - 1) {
            for (int j = cur + 1; j <= N; ++j) row_ptr[j] = E;
        }
    }
    if (t < N * DK) {
        const int s = t >> 5;          // node
        const int r = t & 31;          // dword within row
        const int c = r >> 2;          // chunk
        const int q = r & 3;           // 0:K01 1:K23 2:V01 3:V23
        const float* srcp = (q < 2) ? K : V;
        const int d0 = c * 4 + (q & 1) * 2;
        h2 h;
        h.x = (_Float16)srcp[s * DK + d0];
        h.y = (_Float16)srcp[s * DK + d0 + 1];
        KVH[t] = as_u32(h);
    }
}

// Fallback-path row_ptr builder (ws too small for KV).
__global__ void build_row_ptr_kernel(const int* __restrict__ dst, int E, int N,
                                     int* __restrict__ row_ptr) {
    int e = blockIdx.x * blockDim.x + threadIdx.x;
    if (e >= E) return;
    int cur  = dst[e];
    int prev = (e == 0) ? -1 : dst[e - 1];
    for (int j = prev + 1; j <= cur; ++j) row_ptr[j] = e;
    if (e == E - 1) {
        for (int j = cur + 1; j <= N; ++j) row_ptr[j] = E;
    }
}

// R12 = R11 with the lockstep widened to ALL 4 of the wave's nodes: every
// step issues 8 src + 8 KV gather chains unconditionally (clamped indices;
// finished/empty segments re-read their last line -> L1 hit, weight masked
// to 0 at the exp — never a branch). Serial steps per wave drop from
// 2*E[max2 ceil(d/16)]≈3.4 (R11) to E[max4]≈1.9, with 2x the lines in
// flight (per CU ~160). Partition unchanged: block = 4 waves = 16 nodes,
// grid 6250 (~24 blocks/CU) for TLP. f16 math: v_dot2_f32_f16 dot,
// v_pk_fma_f16 accumulate (R10-proven). Epilogue per node: xor(8) -> 4
// partials, l-reduce, normalize, half2s to block A-tile; one barrier;
// wave 0 folds partial-reduction + W_o projection for all 16 nodes with
// 8 f16 MFMAs:  out(16x32) = part(16x[4x32]) @ Wrep([4x32]x32) + b.
__global__ __launch_bounds__(256) void gat_fused_kernel(
    const float* __restrict__ X, const uint4* __restrict__ KV,
    const float* __restrict__ Wo, const float* __restrict__ bo,
    const int* __restrict__ src, const int* __restrict__ row_ptr,
    float* __restrict__ out, int N) {

    __shared__ uint4 s_part[16 * 17];   // block A-tile, row stride 17 (pad->b128)

    const int tid  = threadIdx.x;
    const int w    = tid >> 6;    // wave 0..3
    const int lane = tid & 63;
    const int g    = lane >> 3;   // edge slot 0..7
    const int c    = lane & 7;    // dim chunk 0..7

    const int n_blk = blockIdx.x * 16;       // block's first node (< N always)
    const int n_w   = n_blk + w * 4;         // wave's first node

    // row_ptr[n_w .. n_w+4] into lanes 0..4 (clamped; row_ptr[N] = E)
    const int rpv = row_ptr[min(n_w + min(lane, 4), N)];

    const float4* X4 = (const float4*)X;
    unsigned* part32 = (unsigned*)s_part;
    const float scale = 0.03125f;

    // wave-uniform segment bounds for the 4 nodes (SGPRs)
    int eb[5];
#pragma unroll
    for (int i = 0; i < 5; ++i) eb[i] = __builtin_amdgcn_readlane(rpv, i);

    int   e[4], cap[4];
    float l[4];
    h2    q01[4], q23[4], a01[4], a23[4];
#pragma unroll
    for (int i = 0; i < 4; ++i) {
        e[i]   = eb[i];
        cap[i] = max(eb[i + 1] - 1, 0);
        l[i]   = 0.0f;
        a01[i] = (h2)0;  a23[i] = (h2)0;
        const float4 q = X4[min(n_w + i, N - 1) * 8 + c];
        q01[i].x = (_Float16)(q.x * scale);  q01[i].y = (_Float16)(q.y * scale);
        q23[i].x = (_Float16)(q.z * scale);  q23[i].y = (_Float16)(q.w * scale);
    }

    while (e[0] < eb[1] || e[1] < eb[2] || e[2] < eb[3] || e[3] < eb[4]) {
        // ---- issue all 8 src then all 8 KV chains, no branches ----
        int s0[4], s1[4];
#pragma unroll
        for (int i = 0; i < 4; ++i) {
            s0[i] = src[min(e[i] + g,     cap[i])];
            s1[i] = src[min(e[i] + 8 + g, cap[i])];
        }
        uint4 A[4], B[4];
#pragma unroll
        for (int i = 0; i < 4; ++i) {
            A[i] = KV[s0[i] * 8 + c];
            B[i] = KV[s1[i] * 8 + c];
        }

        float p0[4], p1[4];
#pragma unroll
        for (int i = 0; i < 4; ++i) {
            p0[i] = FDOT2(as_h2(A[i].y), q23[i], FDOT2(as_h2(A[i].x), q01[i], 0.0f));
            p1[i] = FDOT2(as_h2(B[i].y), q23[i], FDOT2(as_h2(B[i].x), q01[i], 0.0f));
        }
        // stage-interleaved xor(1,2,4) reductions over the 8 dot chains
#pragma unroll
        for (int m = 1; m <= 4; m <<= 1) {
#pragma unroll
            for (int i = 0; i < 4; ++i) {
                p0[i] += __shfl_xor(p0[i], m);
                p1[i] += __shfl_xor(p1[i], m);
            }
        }
#pragma unroll
        for (int i = 0; i < 4; ++i) {
            const int end_i = eb[i + 1];
            const float w0 = (e[i] + g     < end_i) ? __expf(p0[i]) : 0.0f;
            const float w1 = (e[i] + 8 + g < end_i) ? __expf(p1[i]) : 0.0f;
            l[i] += w0 + w1;
            h2 wh0; wh0.x = (_Float16)w0; wh0.y = wh0.x;
            h2 wh1; wh1.x = (_Float16)w1; wh1.y = wh1.x;
            a01[i] += wh0 * as_h2(A[i].z);  a23[i] += wh0 * as_h2(A[i].w);
            a01[i] += wh1 * as_h2(B[i].z);  a23[i] += wh1 * as_h2(B[i].w);
            e[i] += 16;
        }
    }

    // ---- per-node reductions + A-tile writes ----
#pragma unroll
    for (int i = 0; i < 4; ++i) {
        l[i]   += __shfl_xor(l[i], 8);
        a01[i] += shfl_xor_h2(a01[i], 8);
        a23[i] += shfl_xor_h2(a23[i], 8);
        l[i] += __shfl_xor(l[i], 16);  l[i] += __shfl_xor(l[i], 32);

        const float inv = (eb[i + 1] > eb[i]) ? (1.0f / l[i]) : 0.0f;
        h2 iv; iv.x = (_Float16)inv; iv.y = iv.x;
        a01[i] *= iv;
        a23[i] *= iv;

        if ((g & 1) == 0) {                  // even groups hold pair sums
            const int p   = g >> 1;
            const int row = w * 4 + i;
            const int off = row * 68 + p * 16 + c * 2;   // uint32 units
            part32[off]     = as_u32(a01[i]);
            part32[off + 1] = as_u32(a23[i]);
        }
    }

    __syncthreads();

    // wave 0: projection + partial-group reduction for the block's 16 nodes
    if (w == 0) {
        const int quad = lane >> 4;   // 0..3
        const int col  = lane & 15;

        union BF { h8 v; _Float16 u[8]; };
        BF bf0, bf1;
#pragma unroll
        for (int j2 = 0; j2 < 8; ++j2) {
            bf0.u[j2] = (_Float16)Wo[(quad * 8 + j2) * OUT_DIM + col];
            bf1.u[j2] = (_Float16)Wo[(quad * 8 + j2) * OUT_DIM + 16 + col];
        }
        const float bias0 = bo[col];
        const float bias1 = bo[16 + col];

        union AF { uint4 u; h8 v; };
        f32x4 C0 = {bias0, bias0, bias0, bias0};
        f32x4 C1 = {bias1, bias1, bias1, bias1};
#pragma unroll
        for (int cc = 0; cc < 4; ++cc) {
            AF a;
            a.u = s_part[col * 17 + cc * 4 + quad];      // ds_read_b128
            C0 = __builtin_amdgcn_mfma_f32_16x16x32_f16(a.v, bf0.v, C0, 0, 0, 0);
            C1 = __builtin_amdgcn_mfma_f32_16x16x32_f16(a.v, bf1.v, C1, 0, 0, 0);
        }
        // C/D layout: col = lane&15, row = quad*4 + reg (verified mapping)
#pragma unroll
        for (int r = 0; r < 4; ++r) {
            const int n = n_blk + quad * 4 + r;
            if (n < N) {
                out[n * OUT_DIM + col]      = C0[r];
                out[n * OUT_DIM + 16 + col] = C1[r];
            }
        }
    }
}

// ---- fallback (R4-proven fp32 path, used only if ws too small for KV) ----
__global__ __launch_bounds__(256) void gat_node_f32_kernel(
    const float* __restrict__ X, const float* __restrict__ Km,
    const float* __restrict__ Vm, const float* __restrict__ Wo,
    const float* __restrict__ bo, const int* __restrict__ src,
    const int* __restrict__ row_ptr, float* __restrict__ out, int N) {
    const int tid  = threadIdx.x;
    const int wave = tid >> 6;
    const int lane = tid & 63;
    const int g    = lane >> 3;
    const int c    = lane & 7;
    const int j    = lane & 31;
    const int half = lane >> 5;
    const int n = blockIdx.x * 4 + wave;
    if (n >= N) return;
    const int begin = row_ptr[n];
    const int end   = row_ptr[n + 1];
    const float4* X4 = (const float4*)X;
    const float4* K4 = (const float4*)Km;
    const float4* V4 = (const float4*)Vm;
    const float4 q4 = X4[n * 8 + c];
    float  l   = 0.0f;
    float4 acc = make_float4(0.0f, 0.0f, 0.0f, 0.0f);
    for (int e0 = begin; e0 < end; e0 += 16) {
        const int  ea = e0 + g;
        const int  eb = ea + 8;
        const bool va = ea < end;
        const bool vb = eb < end;
        const int sa = src[min(ea, end - 1)];
        const int sb = src[min(eb, end - 1)];
        const float4 ka  = K4[sa * 8 + c];
        const float4 kb  = K4[sb * 8 + c];
        const float4 vva = V4[sa * 8 + c];
        const float4 vvb = V4[sb * 8 + c];
        float pa = fmaf(ka.x, q4.x, fmaf(ka.y, q4.y, fmaf(ka.z, q4.z, ka.w * q4.w)));
        float pb = fmaf(kb.x, q4.x, fmaf(kb.y, q4.y, fmaf(kb.z, q4.z, kb.w * q4.w)));
        pa += __shfl_xor(pa, 1);  pb += __shfl_xor(pb, 1);
        pa += __shfl_xor(pa, 2);  pb += __shfl_xor(pb, 2);
        pa += __shfl_xor(pa, 4);  pb += __shfl_xor(pb, 4);
        const float wa = va ? __expf(pa * 0.03125f) : 0.0f;
        const float wb = vb ? __expf(pb * 0.03125f) : 0.0f;
        l += wa + wb;
        acc.x = fmaf(wa, vva.x, acc.x);  acc.y = fmaf(wa, vva.y, acc.y);
        acc.z = fmaf(wa, vva.z, acc.z);  acc.w = fmaf(wa, vva.w, acc.w);
        acc.x = fmaf(wb, vvb.x, acc.x);  acc.y = fmaf(wb, vvb.y, acc.y);
        acc.z = fmaf(wb, vvb.z, acc.z);  acc.w = fmaf(wb, vvb.w, acc.w);
    }
#pragma unroll
    for (int m = 8; m <= 32; m <<= 1) {
        l     += __shfl_xor(l, m);
        acc.x += __shfl_xor(acc.x, m);
        acc.y += __shfl_xor(acc.y, m);
        acc.z += __shfl_xor(acc.z, m);
        acc.w += __shfl_xor(acc.w, m);
    }
    const float inv = (end > begin) ? (1.0f / l) : 0.0f;
    float ag[4] = {acc.x, acc.y, acc.z, acc.w};
    float s = 0.0f;
#pragma unroll
    for (int k = 0; k < 32; ++k) {
        const float a = __int_as_float(
            __builtin_amdgcn_readlane(__float_as_int(ag[k & 3]), k >> 2));
        s = fmaf(a, Wo[k * OUT_DIM + j], s);
    }
    if (half == 0) {
        out[n * OUT_DIM + j] = fmaf(s, inv, bo[j]);
    }
}

extern "C" void kernel_launch(void* const* d_in, const int* in_sizes, int n_in,
                              void* d_out, int out_size, void* d_ws, size_t ws_size,
                              hipStream_t stream) {
    const float* X  = (const float*)d_in[0];
    const float* Km = (const float*)d_in[1];
    const float* Vm = (const float*)d_in[2];
    const float* Wo = (const float*)d_in[3];
    const float* bo = (const float*)d_in[4];
    const int* src  = (const int*)d_in[5];
    const int* dst  = (const int*)d_in[6];

    const int N = in_sizes[0] / DK;
    const int E = in_sizes[5];

    int* row_ptr = (int*)d_ws;                              // (N+1) ints
    const size_t kv_off = (((size_t)(N + 1) * 4) + 127) & ~(size_t)127;
    unsigned* KV = (unsigned*)((char*)d_ws + kv_off);       // N*DK uint32
    const size_t need = kv_off + (size_t)N * DK * 4;
    float* out = (float*)d_out;

    const int tb = 256;

    if (ws_size >= need) {
        const int total  = N * DK;
        const int prep_n = (E > total) ? E : total;
        prep_kernel<<<(prep_n + tb - 1) / tb, tb, 0, stream>>>(dst, Km, Vm, E, N,
                                                               row_ptr, KV);
        const int grid = (N + 15) / 16;     // 16 nodes per block, 4 per wave
        gat_fused_kernel<<<grid, 256, 0, stream>>>(X, (const uint4*)KV, Wo, bo,
                                                   src, row_ptr, out, N);
    } else {
        build_row_ptr_kernel<<<(E + tb - 1) / tb, tb, 0, stream>>>(dst, E, N, row_ptr);
        const int grid = (N + 3) / 4;
        gat_node_f32_kernel<<<grid, 256, 0, stream>>>(X, Km, Vm, Wo, bo,
                                                      src, row_ptr, out, N);
    }
}